// Round 1
// baseline (1689.342 us; speedup 1.0000x reference)
//
#include <hip/hip_runtime.h>
#include <math.h>

// Problem constants (B,T,D) = (16,1024,1024)
#define BB 16
#define TT 1024
#define DD 1024
#define M_TOT (BB * TT)   // 16384 GEMM rows

// ---------------- Kernel 1: xt = tanh(0.5 * x) in double ----------------
__global__ void k_tanh_xt(const float* __restrict__ x, double* __restrict__ xt) {
    const size_t i = ((size_t)blockIdx.x * blockDim.x + threadIdx.x) * 4;
    const float4 v = *(const float4*)(x + i);
    xt[i + 0] = tanh((double)v.x * 0.5);
    xt[i + 1] = tanh((double)v.y * 0.5);
    xt[i + 2] = tanh((double)v.z * 0.5);
    xt[i + 3] = tanh((double)v.w * 0.5);
}

// ---------------- Kernel 2: fp64 GEMM ic = tanh(xt @ W^T), t-major output ----------------
// A: [M_TOT, DD] double (xt).  W: [DD, DD] float (row e is weights for output e).
// Output icT: [(t*BB + b) * DD + e] double  (t-major for the scan's coalesced reads).
#define BM 128
#define BN 128
#define BK 16

__launch_bounds__(256)
__global__ void k_gemm_tanh(const double* __restrict__ A, const float* __restrict__ W,
                            double* __restrict__ icT) {
    __shared__ double As[BK][BM + 1];  // +1 pad: k-stride 129 doubles breaks bank aliasing
    __shared__ double Ws[BK][BN + 1];

    const int tid = threadIdx.x;
    const int tx = tid & 15;        // column group (e)
    const int ty = tid >> 4;        // row group (m)
    const int m0 = (blockIdx.x >> 3) * BM;  // 128 m-blocks
    const int e0 = (blockIdx.x & 7) * BN;   // 8 e-blocks

    double acc[8][8] = {};

    const int kl = tid & 15;   // staging k index
    const int r0 = tid >> 4;   // staging row base

    for (int kt = 0; kt < DD; kt += BK) {
        __syncthreads();
#pragma unroll
        for (int i = 0; i < 8; ++i) {
            const int mr = r0 + 16 * i;
            As[kl][mr] = A[(size_t)(m0 + mr) * DD + kt + kl];
            Ws[kl][mr] = (double)W[(size_t)(e0 + mr) * DD + kt + kl];
        }
        __syncthreads();
#pragma unroll
        for (int kk = 0; kk < BK; ++kk) {
            double a[8], w[8];
#pragma unroll
            for (int j = 0; j < 8; ++j) a[j] = As[kk][ty + 16 * j];
#pragma unroll
            for (int j = 0; j < 8; ++j) w[j] = Ws[kk][tx + 16 * j];
#pragma unroll
            for (int i = 0; i < 8; ++i)
#pragma unroll
                for (int j = 0; j < 8; ++j)
                    acc[i][j] = fma(a[i], w[j], acc[i][j]);
        }
    }

    // Epilogue: ic = tanh(acc), scatter to t-major layout
#pragma unroll
    for (int i = 0; i < 8; ++i) {
        const int m = m0 + ty + 16 * i;
        const int b = m >> 10;       // m = b*TT + t
        const int t = m & 1023;
        const size_t rowbase = (size_t)(t * BB + b) * DD;
#pragma unroll
        for (int j = 0; j < 8; ++j) {
            const int e = e0 + tx + 16 * j;
            icT[rowbase + e] = tanh(acc[i][j]);
        }
    }
}

// ---------------- Kernel 3: LIF scan + fused output epilogue ----------------
// One thread per (b, e) chain; 16384 threads total. Double-buffered 8-step chunks.
#define CH 8

__global__ void k_scan(const double* __restrict__ icT, const float* __restrict__ noise,
                       const float* __restrict__ x, const float* __restrict__ res_scale,
                       float* __restrict__ out) {
    const int tid = blockIdx.x * blockDim.x + threadIdx.x;  // 0..16383
    const int b = tid >> 10;
    const int e = tid & 1023;

    const double r = 1.0 / (1.0 + exp(-(double)res_scale[0]));
    const double omr = 1.0 - r;
    const double cnoise = 0.005 * 0.15;   // NOISE_SCALE * THRESHOLD (double)

    const size_t bte = (size_t)b * (TT * DD) + e;  // base for [b, t=0, e]

    double icc[CH], icn[CH];
    float nc[CH], nn[CH], xc[CH], xn[CH];

    // preload chunk 0
#pragma unroll
    for (int i = 0; i < CH; ++i) {
        icc[i] = icT[(size_t)(i * BB + b) * DD + e];
        nc[i]  = noise[bte + (size_t)i * DD];
        xc[i]  = x[bte + (size_t)i * DD];
    }

    double mem = 0.0;
    for (int t0 = 0; t0 < TT; t0 += CH) {
        const bool has_next = (t0 + CH) < TT;
        if (has_next) {
            const int tn = t0 + CH;
#pragma unroll
            for (int i = 0; i < CH; ++i) {
                icn[i] = icT[(size_t)((tn + i) * BB + b) * DD + e];
                nn[i]  = noise[bte + (size_t)(tn + i) * DD];
                xn[i]  = x[bte + (size_t)(tn + i) * DD];
            }
        }
#pragma unroll
        for (int i = 0; i < CH; ++i) {
            const int t = t0 + i;
            const double ic = icc[i];
            // mem = ((DECAY*mem + ic) + n*c) + 1e-6   (reference association)
            mem = ((0.95 * mem + ic) + (double)nc[i] * cnoise) + 1e-6;
            const bool s = (mem >= 0.15);
            const double raw = s ? (ic * 0.5) : 0.0;
            const double xt = tanh((double)xc[i] * 0.5);
            const double o = tanh((r * raw + omr * xt) * 0.5);
            out[bte + (size_t)t * DD] = (float)o;
            mem = s ? -0.05 : mem;
        }
        if (has_next) {
#pragma unroll
            for (int i = 0; i < CH; ++i) { icc[i] = icn[i]; nc[i] = nn[i]; xc[i] = xn[i]; }
        }
    }
}

// ---------------- Launch ----------------
extern "C" void kernel_launch(void* const* d_in, const int* in_sizes, int n_in,
                              void* d_out, int out_size, void* d_ws, size_t ws_size,
                              hipStream_t stream) {
    const float* x     = (const float*)d_in[0];   // (B,T,D) f32
    const float* W     = (const float*)d_in[1];   // (D,D) f32
    const float* rs    = (const float*)d_in[2];   // scalar f32
    const float* noise = (const float*)d_in[3];   // (B,T,D) f32
    float* out = (float*)d_out;

    // ws layout: xt (double, 16M) | icT (double, 16M)  => 256 MB total
    double* xt  = (double*)d_ws;
    double* icT = xt + (size_t)M_TOT * DD;

    // K1: xt = tanh(0.5*x), 4 elems/thread
    k_tanh_xt<<<(M_TOT * DD) / (256 * 4), 256, 0, stream>>>(x, xt);

    // K2: fp64 GEMM + tanh, t-major output
    k_gemm_tanh<<<(M_TOT / BM) * (DD / BN), 256, 0, stream>>>(xt, W, icT);

    // K3: LIF scan + fused epilogue. 16384 chains, 64-thread blocks spread over CUs.
    k_scan<<<M_TOT * DD / DD / 64, 64, 0, stream>>>(icT, noise, x, rs, out);
}

// Round 3
// 1166.751 us; speedup vs baseline: 1.4479x; 1.4479x over previous
//
#include <hip/hip_runtime.h>
#include <math.h>

// Problem constants (B,T,D) = (16,1024,1024)
#define BB 16
#define TT 1024
#define DD 1024
#define M_TOT (BB * TT)   // 16384 GEMM rows

typedef double v4d __attribute__((ext_vector_type(4)));

// ---------------- Kernel 1: xt = tanh(0.5 * x) in double ----------------
// fp64 needed: GEMM-input error must stay ~1e-10 so accumulated ic error ~1e-9
// keeps expected spike flips << 1 over 16.7M threshold comparisons.
__global__ void k_tanh_xt(const float* __restrict__ x, double* __restrict__ xt) {
    const size_t i = ((size_t)blockIdx.x * blockDim.x + threadIdx.x) * 4;
    const float4 v = *(const float4*)(x + i);
    xt[i + 0] = tanh((double)v.x * 0.5);
    xt[i + 1] = tanh((double)v.y * 0.5);
    xt[i + 2] = tanh((double)v.z * 0.5);
    xt[i + 3] = tanh((double)v.w * 0.5);
}

// ---------------- Kernel 2: fp64 MFMA GEMM ic = tanh(xt @ W^T), t-major output ----------------
// C/D layout for v_mfma_f64_16x16x4f64 is probed AT RUNTIME (R2 failed on an assumed
// layout): D1=mfma(rowcode,1,0) gives 4*row per slot, D2=mfma(1,rowcode,0) gives 4*col.
// Only assumption: A/B 16-dims map to lane&15 with symmetric k-structure (universal
// CDNA convention for 16x16 shapes).
#define BM 128
#define BN 64
#define BK 16
#define RS (BK + 1)   // LDS row stride (doubles)

__launch_bounds__(256)
__global__ void k_gemm_tanh_mfma(const double* __restrict__ A, const float* __restrict__ W,
                                 double* __restrict__ icT) {
    __shared__ double As[BM][RS];  // [m][k]
    __shared__ double Bs[BN][RS];  // [e][k]

    const int tid = threadIdx.x;
    const int l  = tid & 63;
    const int w  = tid >> 6;          // wave 0..3
    const int wm = (w & 1) * 64;      // wave m offset within block tile
    const int wn = (w >> 1) * 32;     // wave e offset
    const int lr = l & 15;            // M/N index within 16
    const int lg = l >> 4;            // K group 0..3

    const int m0 = (blockIdx.x >> 4) * BM;   // 128 m-blocks
    const int e0 = (blockIdx.x & 15) * BN;   // 16 e-blocks

    // ---- Runtime layout probe ----
    v4d zc = {};
    const double rowcode = (double)lr;
    v4d d1 = __builtin_amdgcn_mfma_f64_16x16x4f64(rowcode, 1.0, zc, 0, 0, 0);  // 4*row
    v4d d2 = __builtin_amdgcn_mfma_f64_16x16x4f64(1.0, rowcode, zc, 0, 0, 0);  // 4*col
    int am[4], bn[4];
#pragma unroll
    for (int ei = 0; ei < 4; ++ei) {
        am[ei] = ((int)d1[ei]) >> 2;
        bn[ei] = ((int)d2[ei]) >> 2;
    }

    v4d acc[4][2] = {};  // 4 m-tiles x 2 n-tiles per wave (64x32)

    for (int kt = 0; kt < DD; kt += BK) {
        __syncthreads();
        // Stage A: 128x16 doubles, 8/thread (16 lanes span one m-row's 16 k's)
#pragma unroll
        for (int i = 0; i < 8; ++i) {
            const int f = tid + 256 * i;
            const int m = f >> 4, k = f & 15;
            As[m][k] = A[(size_t)(m0 + m) * DD + kt + k];
        }
        // Stage B: 64x16 (W row e = weights for output e)
#pragma unroll
        for (int i = 0; i < 4; ++i) {
            const int f = tid + 256 * i;
            const int e = f >> 4, k = f & 15;
            Bs[e][k] = (double)W[(size_t)(e0 + e) * DD + kt + k];
        }
        __syncthreads();
#pragma unroll
        for (int s = 0; s < 4; ++s) {
            const int kk = 4 * s + lg;
            double a[4], b[2];
#pragma unroll
            for (int mt = 0; mt < 4; ++mt) a[mt] = As[wm + 16 * mt + lr][kk];
#pragma unroll
            for (int nt = 0; nt < 2; ++nt) b[nt] = Bs[wn + 16 * nt + lr][kk];
#pragma unroll
            for (int mt = 0; mt < 4; ++mt)
#pragma unroll
                for (int nt = 0; nt < 2; ++nt)
                    acc[mt][nt] = __builtin_amdgcn_mfma_f64_16x16x4f64(a[mt], b[nt], acc[mt][nt], 0, 0, 0);
        }
    }

    // Epilogue: ic = tanh(acc) fp64 (feeds the chaotic mem chain), scatter t-major
    // using the probed per-slot (row, col).
#pragma unroll
    for (int mt = 0; mt < 4; ++mt) {
#pragma unroll
        for (int ei = 0; ei < 4; ++ei) {
            const int m = m0 + wm + 16 * mt + am[ei];
            const int b = m >> 10;       // m = b*TT + t
            const int t = m & 1023;
            const size_t rowbase = (size_t)(t * BB + b) * DD;
#pragma unroll
            for (int nt = 0; nt < 2; ++nt) {
                const int e = e0 + wn + 16 * nt + bn[ei];
                icT[rowbase + e] = tanh(acc[mt][nt][ei]);
            }
        }
    }
}

// ---------------- Kernel 3: LIF scan + fused output epilogue ----------------
// mem chain in fp64 (chaos-critical); output tanh in fast f32 (err ~1e-7 << 6.4e-3 threshold).
#define CH 8

__device__ __forceinline__ float fast_tanhf(float v) {
    const float e = __expf(2.0f * v);
    return 1.0f - 2.0f / (e + 1.0f);
}

__global__ void k_scan(const double* __restrict__ icT, const float* __restrict__ noise,
                       const float* __restrict__ x, const float* __restrict__ res_scale,
                       float* __restrict__ out) {
    const int tid = blockIdx.x * blockDim.x + threadIdx.x;  // 0..16383
    const int b = tid >> 10;
    const int e = tid & 1023;

    const double r = 1.0 / (1.0 + exp(-(double)res_scale[0]));
    const float rf = (float)r;
    const float omrf = (float)(1.0 - r);
    const double cnoise = 0.005 * 0.15;   // NOISE_SCALE * THRESHOLD

    const size_t bte = (size_t)b * (TT * DD) + e;  // base for [b, t=0, e]

    double icc[CH], icn[CH];
    float nc[CH], nn[CH], xc[CH], xn[CH];

#pragma unroll
    for (int i = 0; i < CH; ++i) {
        icc[i] = icT[(size_t)(i * BB + b) * DD + e];
        nc[i]  = noise[bte + (size_t)i * DD];
        xc[i]  = x[bte + (size_t)i * DD];
    }

    double mem = 0.0;
    for (int t0 = 0; t0 < TT; t0 += CH) {
        const bool has_next = (t0 + CH) < TT;
        if (has_next) {
            const int tn = t0 + CH;
#pragma unroll
            for (int i = 0; i < CH; ++i) {
                icn[i] = icT[(size_t)((tn + i) * BB + b) * DD + e];
                nn[i]  = noise[bte + (size_t)(tn + i) * DD];
                xn[i]  = x[bte + (size_t)(tn + i) * DD];
            }
        }
#pragma unroll
        for (int i = 0; i < CH; ++i) {
            const int t = t0 + i;
            const double ic = icc[i];
            // reference association: ((DECAY*mem + ic) + n*c) + 1e-6
            mem = ((0.95 * mem + ic) + (double)nc[i] * cnoise) + 1e-6;
            const bool s = (mem >= 0.15);
            const float raw = s ? (float)ic * 0.5f : 0.0f;
            const float xt = fast_tanhf(0.5f * xc[i]);
            out[bte + (size_t)t * DD] = fast_tanhf((rf * raw + omrf * xt) * 0.5f);
            mem = s ? -0.05 : mem;
        }
        if (has_next) {
#pragma unroll
            for (int i = 0; i < CH; ++i) { icc[i] = icn[i]; nc[i] = nn[i]; xc[i] = xn[i]; }
        }
    }
}

// ---------------- Launch ----------------
extern "C" void kernel_launch(void* const* d_in, const int* in_sizes, int n_in,
                              void* d_out, int out_size, void* d_ws, size_t ws_size,
                              hipStream_t stream) {
    const float* x     = (const float*)d_in[0];   // (B,T,D) f32
    const float* W     = (const float*)d_in[1];   // (D,D) f32
    const float* rs    = (const float*)d_in[2];   // scalar f32
    const float* noise = (const float*)d_in[3];   // (B,T,D) f32
    float* out = (float*)d_out;

    // ws layout: xt (double, 16M) | icT (double, 16M)  => 256 MB total
    double* xt  = (double*)d_ws;
    double* icT = xt + (size_t)M_TOT * DD;

    k_tanh_xt<<<(M_TOT * DD) / (256 * 4), 256, 0, stream>>>(x, xt);

    k_gemm_tanh_mfma<<<(M_TOT / BM) * (DD / BN), 256, 0, stream>>>(xt, W, icT);

    k_scan<<<M_TOT / 64, 64, 0, stream>>>(icT, noise, x, rs, out);
}